// Round 14
// baseline (429.144 us; speedup 1.0000x reference)
//
#include <hip/hip_runtime.h>
#include <hip/hip_bf16.h>
#include <math.h>

// ---- problem dims ----
constexpr int B2   = 2;
constexpr int CIN  = 64;
constexpr int COUT = 128;
constexpr int T    = 8192;
constexpr int L    = 4096;     // T/2
constexpr int DI   = 256;
constexpr int NST  = 16;       // d_state
constexpr int DTR  = 8;
constexpr int Q    = 32;       // scan chunk length
constexpr int NC   = 128;      // L / Q
constexpr int TOK  = B2 * L;   // 8192 tokens

typedef __attribute__((ext_vector_type(8))) short bf16x8s;   // 8 bf16 (4 VGPRs)
typedef __attribute__((ext_vector_type(4))) float f32x4;

__device__ __forceinline__ float sigmoidf_(float x) { return 1.f / (1.f + __expf(-x)); }
__device__ __forceinline__ unsigned short f2bf(float f) {
    unsigned int u = __float_as_uint(f);
    unsigned int r = (u + 0x7FFFu + ((u >> 16) & 1u)) >> 16;
    return (unsigned short)r;
}
__device__ __forceinline__ float bf2f(unsigned short s) {
    return __uint_as_float((unsigned int)s << 16);
}
__device__ __forceinline__ float lo16f(unsigned int v) { return __uint_as_float(v << 16); }
__device__ __forceinline__ float hi16f(unsigned int v) { return __uint_as_float(v & 0xFFFF0000u); }

// ---------------- one-shot prep: stats zero + all weight converts/reorders
__global__ __launch_bounds__(256) void prep_all_kernel(
    const float* __restrict__ W_in, const float* __restrict__ W_out,
    const float* __restrict__ W_xproj, const float* __restrict__ cw,
    unsigned short* __restrict__ Winb, unsigned short* __restrict__ Woutb,
    unsigned short* __restrict__ Wxb, unsigned short* __restrict__ Wrb,
    float* __restrict__ stats) {
    int idx = blockIdx.x * 256 + threadIdx.x;
    if (blockIdx.x == 0 && threadIdx.x < 4) stats[threadIdx.x] = 0.f;
    if (idx < 262144) {
        Winb[idx] = f2bf(W_in[idx]);
    } else if (idx < 393216) {
        int i = idx - 262144; Woutb[i] = f2bf(W_out[i]);
    } else if (idx < 434176) {
        int i = idx - 393216; Wxb[i] = f2bf(W_xproj[i]);
    } else if (idx < 475136) {
        int i = idx - 434176;                 // conv reorder: [co][ci][kp] -> [co][kp*64+ci]
        int co = i / 320, r = i % 320;
        int kp = r >> 6, ci = r & 63;
        Wrb[i] = f2bf(cw[co * 320 + ci * 5 + kp]);
    }
}

// ---------------- x transpose+convert: x[b][ci][t] -> xTb[b][t][ci] (bf16)
__global__ __launch_bounds__(256) void xpose_kernel(
    const float* __restrict__ x, unsigned short* __restrict__ xTb) {
    __shared__ float tile[64][65];
    int b = blockIdx.y, tb = blockIdx.x * 64, tid = threadIdx.x;
    #pragma unroll
    for (int i = 0; i < 16; ++i) {
        int idx = i * 256 + tid; int ci = idx >> 6, tt = idx & 63;
        tile[ci][tt] = x[((size_t)b * CIN + ci) * T + tb + tt];
    }
    __syncthreads();
    #pragma unroll
    for (int i = 0; i < 16; ++i) {
        int idx = i * 256 + tid; int tt = idx >> 6, ci = idx & 63;
        xTb[((size_t)b * T + tb + tt) * 64 + ci] = f2bf(tile[ci][tt]);
    }
}

// ---------------- conv1d stride2 as bf16-MFMA implicit GEMM + GN stats
__global__ __launch_bounds__(256) void conv_mfma_kernel(
    const unsigned short* __restrict__ xTb, const unsigned short* __restrict__ Wrb,
    const float* __restrict__ cb, float* __restrict__ h, float* __restrict__ stats) {
    const int tid = threadIdx.x;
    const int w = tid >> 6, lane = tid & 63, q = lane >> 4, c = lane & 15;
    const int t0g = blockIdx.x * 64;
    const int t0  = t0g + w * 16;
    const int ct0 = blockIdx.y * 64;
    const int b   = t0g >> 12;
    const int l   = (t0 + c) & (L - 1);
    f32x4 acc[4] = {};
    for (int kc = 0; kc < 320; kc += 32) {
        int kp  = kc >> 6;
        int ci0 = (kc & 63) + q * 8;
        int p = 2 * l + kp - 2;
        bf16x8s a = {};
        if (p >= 0 && p < T)
            a = *(const bf16x8s*)&xTb[((size_t)b * T + p) * 64 + ci0];
        #pragma unroll
        for (int i = 0; i < 4; ++i) {
            bf16x8s bb = *(const bf16x8s*)&Wrb[(size_t)(ct0 + i * 16 + c) * 320 + kc + q * 8];
            acc[i] = __builtin_amdgcn_mfma_f32_16x16x32_bf16(a, bb, acc[i], 0, 0, 0);
        }
    }
    float s = 0.f, ss = 0.f;
    #pragma unroll
    for (int i = 0; i < 4; ++i) {
        int cout = ct0 + i * 16 + c;
        float bias = cb[cout];
        #pragma unroll
        for (int r = 0; r < 4; ++r) {
            int tok = t0 + q * 4 + r;
            float v = acc[i][r] + bias;
            h[(size_t)tok * COUT + cout] = v;
            s += v; ss += v * v;
        }
    }
    #pragma unroll
    for (int off = 32; off; off >>= 1) {
        s  += __shfl_down(s,  off, 64);
        ss += __shfl_down(ss, off, 64);
    }
    if (lane == 0) {
        atomicAdd(&stats[b * 2 + 0], s);
        atomicAdd(&stats[b * 2 + 1], ss);
    }
}

// ------------------------------------------------------ GN apply + PReLU
__global__ __launch_bounds__(256) void gn_prelu_kernel(
    float* __restrict__ h, const float* __restrict__ gn_g,
    const float* __restrict__ gn_b, const float* __restrict__ prelu_a,
    const float* __restrict__ stats) {
    int i = blockIdx.x * 256 + threadIdx.x;      // 262144 threads, x4 elements
    size_t base = (size_t)i * 4;
    int b = (base >= (size_t)L * COUT) ? 1 : 0;
    const float n = (float)(L * COUT);
    float mu   = stats[b * 2 + 0] / n;
    float var  = stats[b * 2 + 1] / n - mu * mu;
    float rstd = rsqrtf(var + 1e-5f);
    float a = prelu_a[0];
    float4 v = *(const float4*)&h[base];
    int c = (int)(base % COUT);
    float4 g  = *(const float4*)&gn_g[c];
    float4 bb = *(const float4*)&gn_b[c];
    v.x = (v.x - mu) * rstd * g.x + bb.x; v.x = v.x >= 0.f ? v.x : a * v.x;
    v.y = (v.y - mu) * rstd * g.y + bb.y; v.y = v.y >= 0.f ? v.y : a * v.y;
    v.z = (v.z - mu) * rstd * g.z + bb.z; v.z = v.z >= 0.f ? v.z : a * v.z;
    v.w = (v.w - mu) * rstd * g.w + bb.w; v.w = v.w >= 0.f ? v.w : a * v.w;
    *(float4*)&h[base] = v;
}

// ---------------- fused per-token LayerNorm (redundant per N-block) + inproj MFMA
// grid (TOK/64, 16). LDS-staged normalized hn (row pad 136 bf16).
__global__ __launch_bounds__(256) void ln_inproj_kernel(
    const float* __restrict__ h, const float* __restrict__ lng,
    const float* __restrict__ lnb, const unsigned short* __restrict__ Winb,
    unsigned short* __restrict__ xpb0, unsigned short* __restrict__ zb0,
    unsigned short* __restrict__ xpb1, unsigned short* __restrict__ zb1, int layer) {
    __shared__ unsigned short hnl[64 * 136];
    const int tid = threadIdx.x;
    const int tBase = blockIdx.x * 64;
    // ---- LN phase: thread = (token tl = tid>>2, part = tid&3 covering 32 ch) ----
    {
        int tl = tid >> 2, part = tid & 3;
        const float* row = h + (size_t)(tBase + tl) * COUT + part * 32;
        float vals[32];
        float s = 0.f, ss = 0.f;
        #pragma unroll
        for (int j = 0; j < 8; ++j) {
            float4 v = *(const float4*)&row[j * 4];
            vals[j * 4 + 0] = v.x; vals[j * 4 + 1] = v.y;
            vals[j * 4 + 2] = v.z; vals[j * 4 + 3] = v.w;
            s += v.x + v.y + v.z + v.w;
            ss += v.x * v.x + v.y * v.y + v.z * v.z + v.w * v.w;
        }
        s  += __shfl_xor(s, 1, 4);  s  += __shfl_xor(s, 2, 4);
        ss += __shfl_xor(ss, 1, 4); ss += __shfl_xor(ss, 2, 4);
        float mu = s * (1.f / 128.f);
        float var = ss * (1.f / 128.f) - mu * mu;
        float rstd = rsqrtf(var + 1e-5f);
        unsigned short* dst = &hnl[tl * 136 + part * 32];
        #pragma unroll
        for (int j = 0; j < 32; ++j) {
            int ch = part * 32 + j;
            dst[j] = f2bf((vals[j] - mu) * rstd * lng[ch] + lnb[ch]);
        }
    }
    __syncthreads();
    // ---- MFMA phase (identical math to inproj_mfma, A from LDS) ----
    const int w = tid >> 6, lane = tid & 63, q = lane >> 4, c = lane & 15;
    const int nBase = blockIdx.y * 64;
    const int inst = nBase >> 9;
    const int e0 = nBase & 511;
    const unsigned short* Wb = Winb + (size_t)(layer * 2 + inst) * 512 * 128;
    f32x4 acc[4] = {};
    for (int kc = 0; kc < 128; kc += 32) {
        bf16x8s a = *(const bf16x8s*)&hnl[(w * 16 + c) * 136 + kc + q * 8];
        #pragma unroll
        for (int i = 0; i < 4; ++i) {
            bf16x8s bb = *(const bf16x8s*)&Wb[(size_t)(e0 + i * 16 + c) * 128 + kc + q * 8];
            acc[i] = __builtin_amdgcn_mfma_f32_16x16x32_bf16(a, bb, acc[i], 0, 0, 0);
        }
    }
    const int t0 = tBase + w * 16;
    #pragma unroll
    for (int i = 0; i < 4; ++i) {
        int e = e0 + i * 16 + c;
        bool isz = (e >= 256);
        int eo = e & 255;
        #pragma unroll
        for (int r = 0; r < 4; ++r) {
            int tok = t0 + q * 4 + r;
            float v = acc[i][r];
            if (isz) {
                float sv = v * sigmoidf_(v);
                (inst ? zb1 : zb0)[(size_t)tok * DI + eo] = f2bf(sv);
            } else {
                (inst ? xpb1 : xpb0)[(size_t)tok * DI + eo] = f2bf(v);
            }
        }
    }
}

// ---------------- depthwise causal conv (d=4) + SiLU — bf16 in/out, 4 ch/thread
__global__ __launch_bounds__(256) void dwconv_kernel(
    const unsigned short* __restrict__ xpb0, const unsigned short* __restrict__ xpb1,
    const float* __restrict__ cw, const float* __restrict__ cbias,
    unsigned short* __restrict__ ub0, unsigned short* __restrict__ ub1, int layer) {
    int flat = blockIdx.x * 256 + threadIdx.x;   // 2*2*4096*64 = 1,048,576
    int dq   = flat & 63;
    int l    = (flat >> 6) & (L - 1);
    int b    = (flat >> 18) & 1;
    int inst = flat >> 19;
    const unsigned short* xp = inst ? xpb1 : xpb0;
    unsigned short* u = inst ? ub1 : ub0;
    int m = layer * 2 + inst;
    int d0 = dq * 4;
    float4 w0 = *(const float4*)&cw[(size_t)(m * DI + d0 + 0) * 4];
    float4 w1 = *(const float4*)&cw[(size_t)(m * DI + d0 + 1) * 4];
    float4 w2 = *(const float4*)&cw[(size_t)(m * DI + d0 + 2) * 4];
    float4 w3 = *(const float4*)&cw[(size_t)(m * DI + d0 + 3) * 4];
    float4 acc = *(const float4*)&cbias[m * DI + d0];
    size_t base = ((size_t)b * L) * DI + d0;
    #pragma unroll
    for (int k = 0; k < 4; ++k) {
        int lt = (inst == 0) ? (l - 3 + k) : (l + 3 - k);   // tap order matches weight idx k
        if (lt < 0 || lt >= L) continue;
        ushort4 vv = *(const ushort4*)&xp[base + (size_t)lt * DI];
        float vx = bf2f(vv.x), vy = bf2f(vv.y), vz = bf2f(vv.z), vw = bf2f(vv.w);
        float wk0 = ((const float*)&w0)[k], wk1 = ((const float*)&w1)[k];
        float wk2 = ((const float*)&w2)[k], wk3 = ((const float*)&w3)[k];
        acc.x = fmaf(wk0, vx, acc.x); acc.y = fmaf(wk1, vy, acc.y);
        acc.z = fmaf(wk2, vz, acc.z); acc.w = fmaf(wk3, vw, acc.w);
    }
    ushort4 o;
    o.x = f2bf(acc.x * sigmoidf_(acc.x)); o.y = f2bf(acc.y * sigmoidf_(acc.y));
    o.z = f2bf(acc.z * sigmoidf_(acc.z)); o.w = f2bf(acc.w * sigmoidf_(acc.w));
    *(ushort4*)&u[base + (size_t)l * DI] = o;
}

// ---------------- xproj as bf16-MFMA (M=64tok/blk, N=40 in 3 tiles, K=256)
// + fused dt-proj/softplus epilogue writing du packed (lo=u, hi=dl) and bc packed (lo=B, hi=C)
__global__ __launch_bounds__(256) void xproj_mfma_kernel(
    const unsigned short* __restrict__ ub0, const unsigned short* __restrict__ ub1,
    const unsigned short* __restrict__ Wxb, const float* __restrict__ Wdt,
    const float* __restrict__ bdt,
    unsigned int* __restrict__ du0, unsigned int* __restrict__ du1,
    unsigned int* __restrict__ bc0, unsigned int* __restrict__ bc1, int layer) {
    __shared__ float xd[64 * 9];
    const int tid = threadIdx.x;
    const int w = tid >> 6, lane = tid & 63, q = lane >> 4, c = lane & 15;
    const int tBase = blockIdx.x * 64;
    const int t0 = tBase + w * 16;
    const int inst = blockIdx.y;
    const int m = layer * 2 + inst;
    const unsigned short* u = inst ? ub1 : ub0;
    const unsigned short* Wb = Wxb + (size_t)m * 40 * 256;
    f32x4 acc[3] = {};
    for (int kc = 0; kc < 256; kc += 32) {
        bf16x8s a = *(const bf16x8s*)&u[(size_t)(t0 + c) * DI + kc + q * 8];
        #pragma unroll
        for (int i = 0; i < 3; ++i) {
            int e = i * 16 + c;
            bf16x8s bb = {};
            if (e < 40) bb = *(const bf16x8s*)&Wb[(size_t)e * 256 + kc + q * 8];
            acc[i] = __builtin_amdgcn_mfma_f32_16x16x32_bf16(a, bb, acc[i], 0, 0, 0);
        }
    }
    unsigned short* bcw = (unsigned short*)(inst ? bc1 : bc0);
    #pragma unroll
    for (int r = 0; r < 4; ++r) {
        int tokr = w * 16 + q * 4 + r;          // block-relative token
        size_t tok = tBase + tokr;
        if (c < 8) {
            xd[tokr * 9 + c] = acc[0][r];                       // dt cols 0..7
            bcw[(tok * 16 + 8 + c) * 2 + 0] = f2bf(acc[1][r]);  // B n=8+c
            bcw[(tok * 16 + 8 + c) * 2 + 1] = f2bf(acc[2][r]);  // C n=8+c
        } else {
            bcw[(tok * 16 + (c - 8)) * 2 + 0] = f2bf(acc[0][r]); // B n=c-8
            bcw[(tok * 16 + (c - 8)) * 2 + 1] = f2bf(acc[1][r]); // C n=c-8
        }
    }
    __syncthreads();
    {
        int d = tid;
        float wr[8];
        #pragma unroll
        for (int r = 0; r < 8; ++r) wr[r] = Wdt[((size_t)m * DI + d) * DTR + r];
        float bb = bdt[m * DI + d];
        unsigned int* duw = inst ? du1 : du0;
        #pragma unroll 4
        for (int tt = 0; tt < 64; ++tt) {
            float a2 = bb;
            #pragma unroll
            for (int r = 0; r < 8; ++r) a2 = fmaf(xd[tt * 9 + r], wr[r], a2);
            float sp = fmaxf(a2, 0.f) + __logf(1.f + __expf(-fabsf(a2)));
            size_t idx = (size_t)(tBase + tt) * DI + d;
            unsigned int uu = u[idx];                       // u bf16 bits (lo)
            duw[idx] = ((unsigned int)f2bf(sp) << 16) | uu; // hi=dl, lo=u
        }
    }
}

// ---------------------------------------------- scan phase 1: chunk-local (packed bf16)
__global__ __launch_bounds__(256) void scan1_kernel(
    const unsigned int* __restrict__ du0, const unsigned int* __restrict__ du1,
    const unsigned int* __restrict__ bc0, const unsigned int* __restrict__ bc1,
    const float* __restrict__ A_log,
    float* __restrict__ hend, float* __restrict__ dsumb, int layer) {
    const int tid = threadIdx.x;
    const int nq = tid & 3, dlane = tid >> 2;
    const int chunk = blockIdx.x & (NC - 1), dtile = blockIdx.x >> 7;
    const int b = blockIdx.y, inst = blockIdx.z;
    const int m = layer * 2 + inst, dir = inst;
    const int d = dtile * 64 + dlane;
    const unsigned int* du = inst ? du1 : du0;
    const unsigned int* bc = inst ? bc1 : bc0;
    float4 av = *(const float4*)&A_log[((size_t)m * DI + d) * NST + nq * 4];
    const float a0 = -expf(av.x), a1 = -expf(av.y), a2 = -expf(av.z), a3 = -expf(av.w);
    const int s0 = chunk * Q;
    const int l0 = dir ? (L - 1 - s0) : s0;
    const int stp = dir ? -1 : 1;
    long iDU = ((long)(b * L + l0)) * DI + d;
    int  iB  = ((b * L + l0) << 4) + nq * 4;
    const long sDU = (long)stp * DI;
    const int  sB  = stp * NST;
    float h0 = 0.f, h1 = 0.f, h2 = 0.f, h3 = 0.f, dsum = 0.f;
    #pragma unroll 4
    for (int t = 0; t < Q; ++t) {
        unsigned int dv = du[iDU];
        uint4 bcv = *(const uint4*)&bc[iB];
        float uu = lo16f(dv), dlt = hi16f(dv);
        float du_ = dlt * uu;
        h0 = fmaf(__expf(dlt * a0), h0, du_ * lo16f(bcv.x));
        h1 = fmaf(__expf(dlt * a1), h1, du_ * lo16f(bcv.y));
        h2 = fmaf(__expf(dlt * a2), h2, du_ * lo16f(bcv.z));
        h3 = fmaf(__expf(dlt * a3), h3, du_ * lo16f(bcv.w));
        dsum += dlt;
        iDU += sDU; iB += sB;
    }
    size_t oh = (((size_t)(inst * 2 + b) * DI + d) * NC + chunk) * NST + nq * 4;
    *(float4*)&hend[oh] = make_float4(h0, h1, h2, h3);
    if (nq == 0) dsumb[((size_t)(inst * 2 + b) * NC + chunk) * DI + d] = dsum;
}

// ---------------------------------------------- scan combine (in-place prefix)
__global__ __launch_bounds__(256) void combine_kernel(
    float* __restrict__ hend, const float* __restrict__ dsumb,
    const float* __restrict__ A_log, int layer) {
    int flat = blockIdx.x * 256 + threadIdx.x;   // 16384
    int n = flat & 15;
    int d = (flat >> 4) & 255;
    int b = (flat >> 12) & 1;
    int inst = flat >> 13;
    int m = layer * 2 + inst;
    float a = -expf(A_log[((size_t)m * DI + d) * NST + n]);
    size_t baseE = (((size_t)(inst * 2 + b) * DI + d) * NC) * NST + n;
    size_t baseD = ((size_t)(inst * 2 + b) * NC) * DI + d;
    float hc = 0.f;
    #pragma unroll 4
    for (int c = 0; c < NC; ++c) {
        float tmp = hend[baseE + (size_t)c * NST];
        hend[baseE + (size_t)c * NST] = hc;
        float ds = dsumb[baseD + (size_t)c * DI];
        hc = fmaf(__expf(a * ds), hc, tmp);
    }
}

// ------------- scan phase 2: full scan + y + gate (packed bf16; yg bf16 in place over z)
__global__ __launch_bounds__(256) void scan2_kernel(
    const unsigned int* __restrict__ du0, const unsigned int* __restrict__ du1,
    const unsigned int* __restrict__ bc0, const unsigned int* __restrict__ bc1,
    unsigned short* __restrict__ zb0, unsigned short* __restrict__ zb1,
    const float* __restrict__ hin, const float* __restrict__ A_log,
    const float* __restrict__ Dp, int layer) {
    const int tid = threadIdx.x;
    const int nq = tid & 3, dlane = tid >> 2;
    const int chunk = blockIdx.x & (NC - 1), dtile = blockIdx.x >> 7;
    const int b = blockIdx.y, inst = blockIdx.z;
    const int m = layer * 2 + inst, dir = inst;
    const int d = dtile * 64 + dlane;
    const unsigned int* du = inst ? du1 : du0;
    const unsigned int* bc = inst ? bc1 : bc0;
    unsigned short* zs = inst ? zb1 : zb0;   // read z, overwrite with yg (same lane)
    float4 av = *(const float4*)&A_log[((size_t)m * DI + d) * NST + nq * 4];
    const float a0 = -expf(av.x), a1 = -expf(av.y), a2 = -expf(av.z), a3 = -expf(av.w);
    const float dpar = Dp[m * DI + d];
    const int s0 = chunk * Q;
    const int l0 = dir ? (L - 1 - s0) : s0;
    const int stp = dir ? -1 : 1;
    long iDU = ((long)(b * L + l0)) * DI + d;
    int  iB  = ((b * L + l0) << 4) + nq * 4;
    const long sDU = (long)stp * DI;
    const int  sB  = stp * NST;
    float4 hv = *(const float4*)&hin[(((size_t)(inst * 2 + b) * DI + d) * NC + chunk) * NST + nq * 4];
    float h0 = hv.x, h1 = hv.y, h2 = hv.z, h3 = hv.w;
    #pragma unroll 4
    for (int t = 0; t < Q; ++t) {
        unsigned int dv = du[iDU];
        uint4 bcv = *(const uint4*)&bc[iB];
        float uu = lo16f(dv), dlt = hi16f(dv);
        float du_ = dlt * uu;
        h0 = fmaf(__expf(dlt * a0), h0, du_ * lo16f(bcv.x));
        h1 = fmaf(__expf(dlt * a1), h1, du_ * lo16f(bcv.y));
        h2 = fmaf(__expf(dlt * a2), h2, du_ * lo16f(bcv.z));
        h3 = fmaf(__expf(dlt * a3), h3, du_ * lo16f(bcv.w));
        float yp = h0 * hi16f(bcv.x) + h1 * hi16f(bcv.y) + h2 * hi16f(bcv.z) + h3 * hi16f(bcv.w);
        yp += __shfl_xor(yp, 1, 4);
        yp += __shfl_xor(yp, 2, 4);
        if (nq == 0) {
            float zv = bf2f(zs[iDU]);
            zs[iDU] = f2bf(fmaf(uu, dpar, yp) * zv);
        }
        iDU += sDU; iB += sB;
    }
}

// ---------------- outproj as bf16-MFMA GEMM (both insts summed) + residual into h
__global__ __launch_bounds__(256) void outproj_mfma_kernel(
    const unsigned short* __restrict__ ygb0, const unsigned short* __restrict__ ygb1,
    const unsigned short* __restrict__ Woutb, float* __restrict__ h, int layer) {
    const int tid = threadIdx.x;
    const int w = tid >> 6, lane = tid & 63, q = lane >> 4, c = lane & 15;
    const int t0 = blockIdx.x * 64 + w * 16;
    const int ct0 = blockIdx.y * 32;
    f32x4 acc[2] = {};
    #pragma unroll
    for (int inst = 0; inst < 2; ++inst) {
        const unsigned short* yg = inst ? ygb1 : ygb0;
        const unsigned short* Wb = Woutb + (size_t)(layer * 2 + inst) * COUT * DI;
        for (int kc = 0; kc < 256; kc += 32) {
            bf16x8s a = *(const bf16x8s*)&yg[(size_t)(t0 + c) * DI + kc + q * 8];
            #pragma unroll
            for (int i = 0; i < 2; ++i) {
                bf16x8s bb = *(const bf16x8s*)&Wb[(size_t)(ct0 + i * 16 + c) * DI + kc + q * 8];
                acc[i] = __builtin_amdgcn_mfma_f32_16x16x32_bf16(a, bb, acc[i], 0, 0, 0);
            }
        }
    }
    #pragma unroll
    for (int i = 0; i < 2; ++i) {
        int cout = ct0 + i * 16 + c;
        #pragma unroll
        for (int r = 0; r < 4; ++r) {
            int tok = t0 + q * 4 + r;
            h[(size_t)tok * COUT + cout] += acc[i][r];
        }
    }
}

// ------------------------------------------------ final [B,L,C] -> [B,C,L]
__global__ __launch_bounds__(256) void transpose_kernel(
    const float* __restrict__ h, float* __restrict__ out) {
    __shared__ float tile[32][33];
    int lt0 = blockIdx.x * 32, ct0 = blockIdx.y * 32, b = blockIdx.z;
    int c = threadIdx.x & 31, r = threadIdx.x >> 5;
    #pragma unroll
    for (int j = 0; j < 4; ++j) {
        int ll = r + 8 * j;
        tile[ll][c] = h[((size_t)b * L + lt0 + ll) * COUT + ct0 + c];
    }
    __syncthreads();
    #pragma unroll
    for (int j = 0; j < 4; ++j) {
        int cc = r + 8 * j;
        out[((size_t)b * COUT + ct0 + cc) * L + lt0 + c] = tile[c][cc];
    }
}

// ======================================================================
extern "C" void kernel_launch(void* const* d_in, const int* in_sizes, int n_in,
                              void* d_out, int out_size, void* d_ws, size_t ws_size,
                              hipStream_t stream) {
    const float* x        = (const float*)d_in[0];
    const float* conv_w   = (const float*)d_in[1];
    const float* conv_b   = (const float*)d_in[2];
    const float* gn_g     = (const float*)d_in[3];
    const float* gn_b     = (const float*)d_in[4];
    const float* prelu_a  = (const float*)d_in[5];
    const float* ln_g     = (const float*)d_in[6];
    const float* ln_b     = (const float*)d_in[7];
    const float* W_in     = (const float*)d_in[8];
    const float* conv1d_w = (const float*)d_in[9];
    const float* conv1d_b = (const float*)d_in[10];
    const float* W_xproj  = (const float*)d_in[11];
    const float* W_dt     = (const float*)d_in[12];
    const float* b_dt     = (const float*)d_in[13];
    const float* A_log    = (const float*)d_in[14];
    const float* D_param  = (const float*)d_in[15];
    const float* W_out    = (const float*)d_in[16];

    float* ws = (float*)d_ws;
    float* h = ws;                                             // 1,048,576 f
    unsigned short* xpb0 = (unsigned short*)(ws + 1048576);    // [TOK][256] bf16 (1,048,576 f)
    unsigned short* xpb1 = (unsigned short*)(ws + 2097152);
    unsigned short* zb0  = (unsigned short*)(ws + 3145728);    // silu(z) then yg in place
    unsigned short* zb1  = (unsigned short*)(ws + 4194304);
    unsigned short* ub0  = (unsigned short*)(ws + 5242880);    // [TOK][256] bf16
    unsigned short* ub1  = (unsigned short*)(ws + 6291456);
    unsigned int*   du0  = (unsigned int*)(ws + 7340032);      // [TOK][256] uint (lo=u, hi=dl)
    unsigned int*   du1  = (unsigned int*)(ws + 9437184);
    unsigned int*   bc0  = (unsigned int*)(ws + 11534336);     // [TOK][16] uint (lo=B, hi=C)
    unsigned int*   bc1  = (unsigned int*)(ws + 11665408);
    float* hend  = ws + 11796480;                              // [2,B,256,NC,16] = 2,097,152
    float* dsumb = ws + 13893632;                              // 131,072
    unsigned short* Winb  = (unsigned short*)(ws + 14024704);  // 262,144 bf16
    unsigned short* Wrb   = (unsigned short*)(ws + 14155776);  // 40,960 bf16
    unsigned short* Woutb = (unsigned short*)(ws + 14176256);  // 131,072 bf16
    unsigned short* Wxb   = (unsigned short*)(ws + 14241792);  // 40,960 bf16
    float* stats = ws + 14262272;                              // [4]
    unsigned short* xTb = zb0;                                 // 1M bf16 (pre-loop only)

    prep_all_kernel<<<1856, 256, 0, stream>>>(W_in, W_out, W_xproj, conv_w,
                                              Winb, Woutb, Wxb, Wrb, stats);
    xpose_kernel<<<dim3(T / 64, B2), 256, 0, stream>>>(x, xTb);
    conv_mfma_kernel<<<dim3(TOK / 64, COUT / 64), 256, 0, stream>>>(xTb, Wrb, conv_b, h, stats);
    gn_prelu_kernel<<<(TOK * COUT / 4) / 256, 256, 0, stream>>>(h, gn_g, gn_b, prelu_a, stats);

    for (int layer = 0; layer < 2; ++layer) {
        ln_inproj_kernel<<<dim3(TOK / 64, 16), 256, 0, stream>>>(h, ln_g + layer * COUT,
                                                                 ln_b + layer * COUT, Winb,
                                                                 xpb0, zb0, xpb1, zb1, layer);
        dwconv_kernel<<<4096, 256, 0, stream>>>(xpb0, xpb1, conv1d_w, conv1d_b, ub0, ub1, layer);
        xproj_mfma_kernel<<<dim3(TOK / 64, 2), 256, 0, stream>>>(ub0, ub1, Wxb, W_dt, b_dt,
                                                                 du0, du1, bc0, bc1, layer);
        scan1_kernel<<<dim3(NC * 4, B2, 2), 256, 0, stream>>>(du0, du1, bc0, bc1,
                                                              A_log, hend, dsumb, layer);
        combine_kernel<<<64, 256, 0, stream>>>(hend, dsumb, A_log, layer);
        scan2_kernel<<<dim3(NC * 4, B2, 2), 256, 0, stream>>>(du0, du1, bc0, bc1,
                                                              zb0, zb1, hend, A_log, D_param, layer);
        outproj_mfma_kernel<<<dim3(TOK / 64, 4), 256, 0, stream>>>(zb0, zb1, Woutb, h, layer);
    }
    transpose_kernel<<<dim3(L / 32, COUT / 32, B2), 256, 0, stream>>>(h, (float*)d_out);
}

// Round 15
// 392.973 us; speedup vs baseline: 1.0920x; 1.0920x over previous
//
#include <hip/hip_runtime.h>
#include <hip/hip_bf16.h>
#include <math.h>

// ---- problem dims ----
constexpr int B2   = 2;
constexpr int CIN  = 64;
constexpr int COUT = 128;
constexpr int T    = 8192;
constexpr int L    = 4096;     // T/2
constexpr int DI   = 256;
constexpr int NST  = 16;       // d_state
constexpr int DTR  = 8;
constexpr int Q    = 32;       // scan chunk length
constexpr int NC   = 128;      // L / Q
constexpr int TOK  = B2 * L;   // 8192 tokens

typedef __attribute__((ext_vector_type(8))) short bf16x8s;   // 8 bf16 (4 VGPRs)
typedef __attribute__((ext_vector_type(4))) float f32x4;

__device__ __forceinline__ float sigmoidf_(float x) { return 1.f / (1.f + __expf(-x)); }
__device__ __forceinline__ unsigned short f2bf(float f) {
    unsigned int u = __float_as_uint(f);
    unsigned int r = (u + 0x7FFFu + ((u >> 16) & 1u)) >> 16;
    return (unsigned short)r;
}
__device__ __forceinline__ float bf2f(unsigned short s) {
    return __uint_as_float((unsigned int)s << 16);
}

// ---------------- one-shot prep: stats zero + all weight converts/reorders
__global__ __launch_bounds__(256) void prep_all_kernel(
    const float* __restrict__ W_in, const float* __restrict__ W_out,
    const float* __restrict__ cw,
    unsigned short* __restrict__ Winb, unsigned short* __restrict__ Woutb,
    unsigned short* __restrict__ Wrb, float* __restrict__ stats) {
    int idx = blockIdx.x * 256 + threadIdx.x;
    if (blockIdx.x == 0 && threadIdx.x < 4) stats[threadIdx.x] = 0.f;
    if (idx < 262144) {
        Winb[idx] = f2bf(W_in[idx]);
    } else if (idx < 393216) {
        int i = idx - 262144; Woutb[i] = f2bf(W_out[i]);
    } else if (idx < 434176) {
        int i = idx - 393216;                 // conv reorder: [co][ci][kp] -> [co][kp*64+ci]
        int co = i / 320, r = i % 320;
        int kp = r >> 6, ci = r & 63;
        Wrb[i] = f2bf(cw[co * 320 + ci * 5 + kp]);
    }
}

// ---------------- x transpose+convert: x[b][ci][t] -> xTb[b][t][ci] (bf16)
__global__ __launch_bounds__(256) void xpose_kernel(
    const float* __restrict__ x, unsigned short* __restrict__ xTb) {
    __shared__ float tile[64][65];
    int b = blockIdx.y, tb = blockIdx.x * 64, tid = threadIdx.x;
    #pragma unroll
    for (int i = 0; i < 16; ++i) {
        int idx = i * 256 + tid; int ci = idx >> 6, tt = idx & 63;
        tile[ci][tt] = x[((size_t)b * CIN + ci) * T + tb + tt];
    }
    __syncthreads();
    #pragma unroll
    for (int i = 0; i < 16; ++i) {
        int idx = i * 256 + tid; int tt = idx >> 6, ci = idx & 63;
        xTb[((size_t)b * T + tb + tt) * 64 + ci] = f2bf(tile[ci][tt]);
    }
}

// ---------------- conv1d stride2 as bf16-MFMA implicit GEMM + GN stats
__global__ __launch_bounds__(256) void conv_mfma_kernel(
    const unsigned short* __restrict__ xTb, const unsigned short* __restrict__ Wrb,
    const float* __restrict__ cb, float* __restrict__ h, float* __restrict__ stats) {
    const int tid = threadIdx.x;
    const int w = tid >> 6, lane = tid & 63, q = lane >> 4, c = lane & 15;
    const int t0g = blockIdx.x * 64;
    const int t0  = t0g + w * 16;
    const int ct0 = blockIdx.y * 64;
    const int b   = t0g >> 12;
    const int l   = (t0 + c) & (L - 1);
    f32x4 acc[4] = {};
    for (int kc = 0; kc < 320; kc += 32) {
        int kp  = kc >> 6;
        int ci0 = (kc & 63) + q * 8;
        int p = 2 * l + kp - 2;
        bf16x8s a = {};
        if (p >= 0 && p < T)
            a = *(const bf16x8s*)&xTb[((size_t)b * T + p) * 64 + ci0];
        #pragma unroll
        for (int i = 0; i < 4; ++i) {
            bf16x8s bb = *(const bf16x8s*)&Wrb[(size_t)(ct0 + i * 16 + c) * 320 + kc + q * 8];
            acc[i] = __builtin_amdgcn_mfma_f32_16x16x32_bf16(a, bb, acc[i], 0, 0, 0);
        }
    }
    float s = 0.f, ss = 0.f;
    #pragma unroll
    for (int i = 0; i < 4; ++i) {
        int cout = ct0 + i * 16 + c;
        float bias = cb[cout];
        #pragma unroll
        for (int r = 0; r < 4; ++r) {
            int tok = t0 + q * 4 + r;
            float v = acc[i][r] + bias;
            h[(size_t)tok * COUT + cout] = v;
            s += v; ss += v * v;
        }
    }
    #pragma unroll
    for (int off = 32; off; off >>= 1) {
        s  += __shfl_down(s,  off, 64);
        ss += __shfl_down(ss, off, 64);
    }
    if (lane == 0) {
        atomicAdd(&stats[b * 2 + 0], s);
        atomicAdd(&stats[b * 2 + 1], ss);
    }
}

// ------------------------------------------------------ GN apply + PReLU
__global__ __launch_bounds__(256) void gn_prelu_kernel(
    float* __restrict__ h, const float* __restrict__ gn_g,
    const float* __restrict__ gn_b, const float* __restrict__ prelu_a,
    const float* __restrict__ stats) {
    int i = blockIdx.x * 256 + threadIdx.x;      // 262144 threads, x4 elements
    size_t base = (size_t)i * 4;
    int b = (base >= (size_t)L * COUT) ? 1 : 0;
    const float n = (float)(L * COUT);
    float mu   = stats[b * 2 + 0] / n;
    float var  = stats[b * 2 + 1] / n - mu * mu;
    float rstd = rsqrtf(var + 1e-5f);
    float a = prelu_a[0];
    float4 v = *(const float4*)&h[base];
    int c = (int)(base % COUT);
    float4 g  = *(const float4*)&gn_g[c];
    float4 bb = *(const float4*)&gn_b[c];
    v.x = (v.x - mu) * rstd * g.x + bb.x; v.x = v.x >= 0.f ? v.x : a * v.x;
    v.y = (v.y - mu) * rstd * g.y + bb.y; v.y = v.y >= 0.f ? v.y : a * v.y;
    v.z = (v.z - mu) * rstd * g.z + bb.z; v.z = v.z >= 0.f ? v.z : a * v.z;
    v.w = (v.w - mu) * rstd * g.w + bb.w; v.w = v.w >= 0.f ? v.w : a * v.w;
    *(float4*)&h[base] = v;
}

// ------------------------------------------------------ per-token LayerNorm -> bf16
__global__ __launch_bounds__(256) void ln_kernel(
    const float* __restrict__ h, unsigned short* __restrict__ hnb,
    const float* __restrict__ g, const float* __restrict__ bta) {
    int wave = threadIdx.x >> 6, lane = threadIdx.x & 63;
    int t = blockIdx.x * 4 + wave;
    const float* row = h + (size_t)t * COUT;
    float2 v = *(const float2*)&row[lane * 2];
    float s = v.x + v.y, ss = v.x * v.x + v.y * v.y;
    #pragma unroll
    for (int off = 32; off; off >>= 1) {
        s  += __shfl_xor(s,  off, 64);
        ss += __shfl_xor(ss, off, 64);
    }
    float mu = s * (1.f / 128.f);
    float var = ss * (1.f / 128.f) - mu * mu;
    float rstd = rsqrtf(var + 1e-5f);
    float2 gg = *(const float2*)&g[lane * 2];
    float2 bb = *(const float2*)&bta[lane * 2];
    ushort2 o;
    o.x = f2bf((v.x - mu) * rstd * gg.x + bb.x);
    o.y = f2bf((v.y - mu) * rstd * gg.y + bb.y);
    *(ushort2*)&hnb[(size_t)t * COUT + lane * 2] = o;
}

// ---------------- inproj as bf16-MFMA GEMM; z-half -> silu -> bf16 store
__global__ __launch_bounds__(256) void inproj_mfma_kernel(
    const unsigned short* __restrict__ hnb, const unsigned short* __restrict__ Winb,
    float* __restrict__ xp0, unsigned short* __restrict__ zb0,
    float* __restrict__ xp1, unsigned short* __restrict__ zb1, int layer) {
    const int tid = threadIdx.x;
    const int w = tid >> 6, lane = tid & 63, q = lane >> 4, c = lane & 15;
    const int t0 = blockIdx.x * 64 + w * 16;
    const int nBase = blockIdx.y * 64;
    const int inst = nBase >> 9;
    const int e0 = nBase & 511;
    const unsigned short* Wb = Winb + (size_t)(layer * 2 + inst) * 512 * 128;
    f32x4 acc[4] = {};
    for (int kc = 0; kc < 128; kc += 32) {
        bf16x8s a = *(const bf16x8s*)&hnb[(size_t)(t0 + c) * 128 + kc + q * 8];
        #pragma unroll
        for (int i = 0; i < 4; ++i) {
            bf16x8s bb = *(const bf16x8s*)&Wb[(size_t)(e0 + i * 16 + c) * 128 + kc + q * 8];
            acc[i] = __builtin_amdgcn_mfma_f32_16x16x32_bf16(a, bb, acc[i], 0, 0, 0);
        }
    }
    #pragma unroll
    for (int i = 0; i < 4; ++i) {
        int e = e0 + i * 16 + c;
        bool isz = (e >= 256);
        int eo = e & 255;
        #pragma unroll
        for (int r = 0; r < 4; ++r) {
            int tok = t0 + q * 4 + r;
            float v = acc[i][r];
            if (isz) {
                float sv = v * sigmoidf_(v);
                (inst ? zb1 : zb0)[(size_t)tok * DI + eo] = f2bf(sv);
            } else {
                (inst ? xp1 : xp0)[(size_t)tok * DI + eo] = v;
            }
        }
    }
}

// ---------------- depthwise causal conv (d=4) + SiLU — 4 channels/thread (float4)
__global__ __launch_bounds__(256) void dwconv_kernel(
    const float* __restrict__ xp0, const float* __restrict__ xp1,
    const float* __restrict__ cw, const float* __restrict__ cbias,
    float* __restrict__ u0, float* __restrict__ u1, int layer) {
    int flat = blockIdx.x * 256 + threadIdx.x;   // 2*2*4096*64 = 1,048,576
    int dq   = flat & 63;
    int l    = (flat >> 6) & (L - 1);
    int b    = (flat >> 18) & 1;
    int inst = flat >> 19;
    const float* xp = inst ? xp1 : xp0;
    float* u = inst ? u1 : u0;
    int m = layer * 2 + inst;
    int d0 = dq * 4;
    float4 w0 = *(const float4*)&cw[(size_t)(m * DI + d0 + 0) * 4];
    float4 w1 = *(const float4*)&cw[(size_t)(m * DI + d0 + 1) * 4];
    float4 w2 = *(const float4*)&cw[(size_t)(m * DI + d0 + 2) * 4];
    float4 w3 = *(const float4*)&cw[(size_t)(m * DI + d0 + 3) * 4];
    float4 acc = *(const float4*)&cbias[m * DI + d0];
    size_t base = ((size_t)b * L) * DI + d0;
    if (inst == 0) {  // forward: taps l-3..l, weights .x..'.w'
        if (l >= 3) { float4 v = *(const float4*)&xp[base + (size_t)(l - 3) * DI];
            acc.x = fmaf(w0.x, v.x, acc.x); acc.y = fmaf(w1.x, v.y, acc.y);
            acc.z = fmaf(w2.x, v.z, acc.z); acc.w = fmaf(w3.x, v.w, acc.w); }
        if (l >= 2) { float4 v = *(const float4*)&xp[base + (size_t)(l - 2) * DI];
            acc.x = fmaf(w0.y, v.x, acc.x); acc.y = fmaf(w1.y, v.y, acc.y);
            acc.z = fmaf(w2.y, v.z, acc.z); acc.w = fmaf(w3.y, v.w, acc.w); }
        if (l >= 1) { float4 v = *(const float4*)&xp[base + (size_t)(l - 1) * DI];
            acc.x = fmaf(w0.z, v.x, acc.x); acc.y = fmaf(w1.z, v.y, acc.y);
            acc.z = fmaf(w2.z, v.z, acc.z); acc.w = fmaf(w3.z, v.w, acc.w); }
        { float4 v = *(const float4*)&xp[base + (size_t)l * DI];
            acc.x = fmaf(w0.w, v.x, acc.x); acc.y = fmaf(w1.w, v.y, acc.y);
            acc.z = fmaf(w2.w, v.z, acc.z); acc.w = fmaf(w3.w, v.w, acc.w); }
    } else {          // backward (natural coords): taps l..l+3, weights .w..'.x'
        { float4 v = *(const float4*)&xp[base + (size_t)l * DI];
            acc.x = fmaf(w0.w, v.x, acc.x); acc.y = fmaf(w1.w, v.y, acc.y);
            acc.z = fmaf(w2.w, v.z, acc.z); acc.w = fmaf(w3.w, v.w, acc.w); }
        if (l + 1 < L) { float4 v = *(const float4*)&xp[base + (size_t)(l + 1) * DI];
            acc.x = fmaf(w0.z, v.x, acc.x); acc.y = fmaf(w1.z, v.y, acc.y);
            acc.z = fmaf(w2.z, v.z, acc.z); acc.w = fmaf(w3.z, v.w, acc.w); }
        if (l + 2 < L) { float4 v = *(const float4*)&xp[base + (size_t)(l + 2) * DI];
            acc.x = fmaf(w0.y, v.x, acc.x); acc.y = fmaf(w1.y, v.y, acc.y);
            acc.z = fmaf(w2.y, v.z, acc.z); acc.w = fmaf(w3.y, v.w, acc.w); }
        if (l + 3 < L) { float4 v = *(const float4*)&xp[base + (size_t)(l + 3) * DI];
            acc.x = fmaf(w0.x, v.x, acc.x); acc.y = fmaf(w1.x, v.y, acc.y);
            acc.z = fmaf(w2.x, v.z, acc.z); acc.w = fmaf(w3.x, v.w, acc.w); }
    }
    acc.x *= sigmoidf_(acc.x); acc.y *= sigmoidf_(acc.y);
    acc.z *= sigmoidf_(acc.z); acc.w *= sigmoidf_(acc.w);
    *(float4*)&u[base + (size_t)l * DI] = acc;
}

// ------------------------------------- xproj as GEMM (M=32tok/blk, N=40, K=256)
__global__ __launch_bounds__(256) void xproj_kernel(
    const float* __restrict__ u0, const float* __restrict__ u1,
    const float* __restrict__ Wx, const float* __restrict__ Wdt,
    const float* __restrict__ bdt,
    float* __restrict__ dl0, float* __restrict__ dl1,
    float* __restrict__ Bm0, float* __restrict__ Bm1,
    float* __restrict__ Cm0, float* __restrict__ Cm1, int layer) {
    __shared__ float Ws[40 * 132];   // [e][k-sub] current K slab
    __shared__ float As[128 * 33];   // [k][t] half-K u tile
    __shared__ float xd[32 * 9];     // dt outputs
    const int tid   = threadIdx.x;
    const int tBase = blockIdx.x * 32;
    const int inst  = blockIdx.y;
    const int m     = layer * 2 + inst;
    const float* u  = inst ? u1 : u0;
    const float* Wm = Wx + (size_t)m * 40 * 256;
    const int t  = tid & 31;
    const int eq = tid >> 5;                // 0..7
    float acc[5] = {};
    for (int kc = 0; kc < 256; kc += 128) {
        __syncthreads();
        #pragma unroll
        for (int i = 0; i < 5; ++i) {
            int idx = i * 256 + tid;
            int e = idx >> 5, kq = idx & 31;
            float4 w4 = *(const float4*)&Wm[(size_t)e * 256 + kc + kq * 4];
            float* dstw = &Ws[e * 132 + kq * 4];
            dstw[0] = w4.x; dstw[1] = w4.y; dstw[2] = w4.z; dstw[3] = w4.w;
        }
        #pragma unroll
        for (int i = 0; i < 4; ++i) {
            int flat = i * 256 + tid;
            int tt = flat >> 5, kq = flat & 31;
            float4 v = *(const float4*)&u[(size_t)(tBase + tt) * DI + kc + kq * 4];
            As[(kq * 4 + 0) * 33 + tt] = v.x;
            As[(kq * 4 + 1) * 33 + tt] = v.y;
            As[(kq * 4 + 2) * 33 + tt] = v.z;
            As[(kq * 4 + 3) * 33 + tt] = v.w;
        }
        __syncthreads();
        #pragma unroll 4
        for (int kk = 0; kk < 128; ++kk) {
            float a = As[kk * 33 + t];
            acc[0] = fmaf(a, Ws[(eq     ) * 132 + kk], acc[0]);
            acc[1] = fmaf(a, Ws[(eq +  8) * 132 + kk], acc[1]);
            acc[2] = fmaf(a, Ws[(eq + 16) * 132 + kk], acc[2]);
            acc[3] = fmaf(a, Ws[(eq + 24) * 132 + kk], acc[3]);
            acc[4] = fmaf(a, Ws[(eq + 32) * 132 + kk], acc[4]);
        }
    }
    {
        int tok = tBase + t;
        float* Bm = inst ? Bm1 : Bm0;
        float* Cm = inst ? Cm1 : Cm0;
        xd[t * 9 + eq] = acc[0];
        Bm[(size_t)tok * NST + eq]     = acc[1];
        Bm[(size_t)tok * NST + 8 + eq] = acc[2];
        Cm[(size_t)tok * NST + eq]     = acc[3];
        Cm[(size_t)tok * NST + 8 + eq] = acc[4];
    }
    __syncthreads();
    {
        int d = tid;
        float wr[8];
        #pragma unroll
        for (int r = 0; r < 8; ++r) wr[r] = Wdt[((size_t)m * DI + d) * DTR + r];
        float bb = bdt[m * DI + d];
        float* dl = inst ? dl1 : dl0;
        #pragma unroll 4
        for (int tt = 0; tt < 32; ++tt) {
            float a2 = bb;
            #pragma unroll
            for (int r = 0; r < 8; ++r) a2 = fmaf(xd[tt * 9 + r], wr[r], a2);
            float sp = fmaxf(a2, 0.f) + __logf(1.f + __expf(-fabsf(a2)));
            dl[(size_t)(tBase + tt) * DI + d] = sp;
        }
    }
}

// ---------------------------------------------- scan phase 1: chunk-local
// thread = (nq 0..3, dlane 0..63); grid (NC*4, B2, 2).
__global__ __launch_bounds__(256) void scan1_kernel(
    const float* __restrict__ dl0, const float* __restrict__ dl1,
    const float* __restrict__ u0,  const float* __restrict__ u1,
    const float* __restrict__ Bm0, const float* __restrict__ Bm1,
    const float* __restrict__ A_log,
    float* __restrict__ hend, float* __restrict__ dsumb, int layer) {
    const int tid = threadIdx.x;
    const int nq = tid & 3, dlane = tid >> 2;
    const int chunk = blockIdx.x & (NC - 1), dtile = blockIdx.x >> 7;
    const int b = blockIdx.y, inst = blockIdx.z;
    const int m = layer * 2 + inst, dir = inst;
    const int d = dtile * 64 + dlane;
    const float* dl = inst ? dl1 : dl0;
    const float* u  = inst ? u1  : u0;
    const float* Bm = inst ? Bm1 : Bm0;
    float4 av = *(const float4*)&A_log[((size_t)m * DI + d) * NST + nq * 4];
    const float a0 = -expf(av.x), a1 = -expf(av.y), a2 = -expf(av.z), a3 = -expf(av.w);
    const int s0 = chunk * Q;
    const int l0 = dir ? (L - 1 - s0) : s0;
    const int stp = dir ? -1 : 1;
    long iDU = ((long)(b * L + l0)) * DI + d;
    int  iB  = ((b * L + l0) << 4) + nq * 4;
    const long sDU = (long)stp * DI;
    const int  sB  = stp * NST;
    float h0 = 0.f, h1 = 0.f, h2 = 0.f, h3 = 0.f, dsum = 0.f;
    #pragma unroll 4
    for (int t = 0; t < Q; ++t) {
        float dlt = dl[iDU], uu = u[iDU];
        float4 bm = *(const float4*)&Bm[iB];
        float du = dlt * uu;
        h0 = fmaf(__expf(dlt * a0), h0, du * bm.x);
        h1 = fmaf(__expf(dlt * a1), h1, du * bm.y);
        h2 = fmaf(__expf(dlt * a2), h2, du * bm.z);
        h3 = fmaf(__expf(dlt * a3), h3, du * bm.w);
        dsum += dlt;
        iDU += sDU; iB += sB;
    }
    size_t oh = (((size_t)(inst * 2 + b) * DI + d) * NC + chunk) * NST + nq * 4;
    *(float4*)&hend[oh] = make_float4(h0, h1, h2, h3);
    if (nq == 0) dsumb[((size_t)(inst * 2 + b) * NC + chunk) * DI + d] = dsum;
}

// ---------------------------------------------- scan combine (in-place prefix)
__global__ __launch_bounds__(256) void combine_kernel(
    float* __restrict__ hend, const float* __restrict__ dsumb,
    const float* __restrict__ A_log, int layer) {
    int flat = blockIdx.x * 256 + threadIdx.x;   // 16384
    int n = flat & 15;
    int d = (flat >> 4) & 255;
    int b = (flat >> 12) & 1;
    int inst = flat >> 13;
    int m = layer * 2 + inst;
    float a = -expf(A_log[((size_t)m * DI + d) * NST + n]);
    size_t baseE = (((size_t)(inst * 2 + b) * DI + d) * NC) * NST + n;
    size_t baseD = ((size_t)(inst * 2 + b) * NC) * DI + d;
    float hc = 0.f;
    #pragma unroll 4
    for (int c = 0; c < NC; ++c) {
        float tmp = hend[baseE + (size_t)c * NST];
        hend[baseE + (size_t)c * NST] = hc;
        float ds = dsumb[baseD + (size_t)c * DI];
        hc = fmaf(__expf(a * ds), hc, tmp);
    }
}

// ------------- scan phase 2: full scan + y + gate (bf16 z, yg written bf16 IN PLACE over z)
__global__ __launch_bounds__(256) void scan2_kernel(
    const float* __restrict__ dl0, const float* __restrict__ dl1,
    const float* __restrict__ u0,  const float* __restrict__ u1,
    const float* __restrict__ Bm0, const float* __restrict__ Bm1,
    const float* __restrict__ Cm0, const float* __restrict__ Cm1,
    unsigned short* __restrict__ zb0, unsigned short* __restrict__ zb1,
    const float* __restrict__ hin, const float* __restrict__ A_log,
    const float* __restrict__ Dp, int layer) {
    const int tid = threadIdx.x;
    const int nq = tid & 3, dlane = tid >> 2;
    const int chunk = blockIdx.x & (NC - 1), dtile = blockIdx.x >> 7;
    const int b = blockIdx.y, inst = blockIdx.z;
    const int m = layer * 2 + inst, dir = inst;
    const int d = dtile * 64 + dlane;
    const float* dl = inst ? dl1 : dl0;
    const float* u  = inst ? u1  : u0;
    const float* Bm = inst ? Bm1 : Bm0;
    const float* Cm = inst ? Cm1 : Cm0;
    unsigned short* zs = inst ? zb1 : zb0;   // read z, overwrite with yg (same lane)
    float4 av = *(const float4*)&A_log[((size_t)m * DI + d) * NST + nq * 4];
    const float a0 = -expf(av.x), a1 = -expf(av.y), a2 = -expf(av.z), a3 = -expf(av.w);
    const float dpar = Dp[m * DI + d];
    const int s0 = chunk * Q;
    const int l0 = dir ? (L - 1 - s0) : s0;
    const int stp = dir ? -1 : 1;
    long iDU = ((long)(b * L + l0)) * DI + d;
    int  iB  = ((b * L + l0) << 4) + nq * 4;
    const long sDU = (long)stp * DI;
    const int  sB  = stp * NST;
    float4 hv = *(const float4*)&hin[(((size_t)(inst * 2 + b) * DI + d) * NC + chunk) * NST + nq * 4];
    float h0 = hv.x, h1 = hv.y, h2 = hv.z, h3 = hv.w;
    #pragma unroll 4
    for (int t = 0; t < Q; ++t) {
        float dlt = dl[iDU], uu = u[iDU];
        float4 bm = *(const float4*)&Bm[iB];
        float4 cm = *(const float4*)&Cm[iB];
        float du = dlt * uu;
        h0 = fmaf(__expf(dlt * a0), h0, du * bm.x);
        h1 = fmaf(__expf(dlt * a1), h1, du * bm.y);
        h2 = fmaf(__expf(dlt * a2), h2, du * bm.z);
        h3 = fmaf(__expf(dlt * a3), h3, du * bm.w);
        float yp = h0 * cm.x + h1 * cm.y + h2 * cm.z + h3 * cm.w;
        yp += __shfl_xor(yp, 1, 4);
        yp += __shfl_xor(yp, 2, 4);
        if (nq == 0) {
            float zv = bf2f(zs[iDU]);
            zs[iDU] = f2bf(fmaf(uu, dpar, yp) * zv);
        }
        iDU += sDU; iB += sB;
    }
}

// ---------------- outproj as bf16-MFMA GEMM (both insts summed) + residual into h
// M=8192 tok, N=128 cout (32/block), K=256. grid (TOK/64, 4).
__global__ __launch_bounds__(256) void outproj_mfma_kernel(
    const unsigned short* __restrict__ ygb0, const unsigned short* __restrict__ ygb1,
    const unsigned short* __restrict__ Woutb, float* __restrict__ h, int layer) {
    const int tid = threadIdx.x;
    const int w = tid >> 6, lane = tid & 63, q = lane >> 4, c = lane & 15;
    const int t0 = blockIdx.x * 64 + w * 16;
    const int ct0 = blockIdx.y * 32;
    f32x4 acc[2] = {};
    #pragma unroll
    for (int inst = 0; inst < 2; ++inst) {
        const unsigned short* yg = inst ? ygb1 : ygb0;
        const unsigned short* Wb = Woutb + (size_t)(layer * 2 + inst) * COUT * DI;
        for (int kc = 0; kc < 256; kc += 32) {
            bf16x8s a = *(const bf16x8s*)&yg[(size_t)(t0 + c) * DI + kc + q * 8];
            #pragma unroll
            for (int i = 0; i < 2; ++i) {
                bf16x8s bb = *(const bf16x8s*)&Wb[(size_t)(ct0 + i * 16 + c) * DI + kc + q * 8];
                acc[i] = __builtin_amdgcn_mfma_f32_16x16x32_bf16(a, bb, acc[i], 0, 0, 0);
            }
        }
    }
    #pragma unroll
    for (int i = 0; i < 2; ++i) {
        int cout = ct0 + i * 16 + c;
        #pragma unroll
        for (int r = 0; r < 4; ++r) {
            int tok = t0 + q * 4 + r;
            h[(size_t)tok * COUT + cout] += acc[i][r];
        }
    }
}

// ------------------------------------------------ final [B,L,C] -> [B,C,L]
__global__ __launch_bounds__(256) void transpose_kernel(
    const float* __restrict__ h, float* __restrict__ out) {
    __shared__ float tile[32][33];
    int lt0 = blockIdx.x * 32, ct0 = blockIdx.y * 32, b = blockIdx.z;
    int c = threadIdx.x & 31, r = threadIdx.x >> 5;
    #pragma unroll
    for (int j = 0; j < 4; ++j) {
        int ll = r + 8 * j;
        tile[ll][c] = h[((size_t)b * L + lt0 + ll) * COUT + ct0 + c];
    }
    __syncthreads();
    #pragma unroll
    for (int j = 0; j < 4; ++j) {
        int cc = r + 8 * j;
        out[((size_t)b * COUT + ct0 + cc) * L + lt0 + c] = tile[c][cc];
    }
}

// ======================================================================
extern "C" void kernel_launch(void* const* d_in, const int* in_sizes, int n_in,
                              void* d_out, int out_size, void* d_ws, size_t ws_size,
                              hipStream_t stream) {
    const float* x        = (const float*)d_in[0];
    const float* conv_w   = (const float*)d_in[1];
    const float* conv_b   = (const float*)d_in[2];
    const float* gn_g     = (const float*)d_in[3];
    const float* gn_b     = (const float*)d_in[4];
    const float* prelu_a  = (const float*)d_in[5];
    const float* ln_g     = (const float*)d_in[6];
    const float* ln_b     = (const float*)d_in[7];
    const float* W_in     = (const float*)d_in[8];
    const float* conv1d_w = (const float*)d_in[9];
    const float* conv1d_b = (const float*)d_in[10];
    const float* W_xproj  = (const float*)d_in[11];
    const float* W_dt     = (const float*)d_in[12];
    const float* b_dt     = (const float*)d_in[13];
    const float* A_log    = (const float*)d_in[14];
    const float* D_param  = (const float*)d_in[15];
    const float* W_out    = (const float*)d_in[16];

    float* ws = (float*)d_ws;
    float* h     = ws;                         // [B,L,128]               1,048,576
    float* xp0   = ws + 1048576;               // [B,L,256] f32           2,097,152
    float* xp1   = ws + 3145728;               //                         2,097,152
    unsigned short* zb0 = (unsigned short*)(ws + 5242880);   // [B,L,256] bf16; silu(z) then yg in-place
    unsigned short* zb1 = (unsigned short*)(ws + 6291456);   // bf16
    float* u0    = ws + 7340032;               // [B,L,256]               2,097,152
    float* u1    = ws + 9437184;
    float* dl0   = ws + 11534336;
    float* dl1   = ws + 13631488;
    float* Bm0   = ws + 15728640;              // [B,L,16]
    float* Bm1   = ws + 15859712;
    float* Cm0   = ws + 15990784;
    float* Cm1   = ws + 16121856;
    float* hend  = ws + 16252928;              // [2,B,256,NC=128,16] = 2,097,152
    float* dsumb = ws + 18350080;              // [2,B,NC,256] = 131,072
    unsigned short* Winb  = (unsigned short*)(ws + 18481152); // 262,144 bf16 (131,072 f)
    unsigned short* Wrb   = (unsigned short*)(ws + 18612224); // 40,960 bf16 (20,480 f)
    unsigned short* Woutb = (unsigned short*)(ws + 18632704); // 131,072 bf16 (65,536 f)
    float* stats = ws + 18698240;              // [4]
    unsigned short* hnb = (unsigned short*)hend;             // 1M bf16 (hend dead outside scans)
    unsigned short* xTb = zb0;                               // 1M bf16 (pre-loop only)

    prep_all_kernel<<<1696, 256, 0, stream>>>(W_in, W_out, conv_w, Winb, Woutb, Wrb, stats);
    xpose_kernel<<<dim3(T / 64, B2), 256, 0, stream>>>(x, xTb);
    conv_mfma_kernel<<<dim3(TOK / 64, COUT / 64), 256, 0, stream>>>(xTb, Wrb, conv_b, h, stats);
    gn_prelu_kernel<<<(TOK * COUT / 4) / 256, 256, 0, stream>>>(h, gn_g, gn_b, prelu_a, stats);

    for (int layer = 0; layer < 2; ++layer) {
        ln_kernel<<<TOK / 4, 256, 0, stream>>>(h, hnb, ln_g + layer * COUT, ln_b + layer * COUT);
        inproj_mfma_kernel<<<dim3(TOK / 64, 16), 256, 0, stream>>>(hnb, Winb, xp0, zb0, xp1, zb1, layer);
        dwconv_kernel<<<4096, 256, 0, stream>>>(xp0, xp1, conv1d_w, conv1d_b, u0, u1, layer);
        xproj_kernel<<<dim3(TOK / 32, 2), 256, 0, stream>>>(u0, u1, W_xproj, W_dt, b_dt,
                                                            dl0, dl1, Bm0, Bm1, Cm0, Cm1, layer);
        scan1_kernel<<<dim3(NC * 4, B2, 2), 256, 0, stream>>>(dl0, dl1, u0, u1, Bm0, Bm1,
                                                              A_log, hend, dsumb, layer);
        combine_kernel<<<64, 256, 0, stream>>>(hend, dsumb, A_log, layer);
        scan2_kernel<<<dim3(NC * 4, B2, 2), 256, 0, stream>>>(dl0, dl1, u0, u1, Bm0, Bm1, Cm0, Cm1,
                                                              zb0, zb1, hend, A_log, D_param, layer);
        outproj_mfma_kernel<<<dim3(TOK / 64, 4), 256, 0, stream>>>(zb0, zb1, Woutb, h, layer);
    }
    transpose_kernel<<<dim3(L / 32, COUT / 32, B2), 256, 0, stream>>>(h, (float*)d_out);
}

// Round 16
// 377.616 us; speedup vs baseline: 1.1365x; 1.0407x over previous
//
#include <hip/hip_runtime.h>
#include <hip/hip_bf16.h>
#include <math.h>

// ---- problem dims ----
constexpr int B2   = 2;
constexpr int CIN  = 64;
constexpr int COUT = 128;
constexpr int T    = 8192;
constexpr int L    = 4096;     // T/2
constexpr int DI   = 256;
constexpr int NST  = 16;       // d_state
constexpr int DTR  = 8;
constexpr int Q    = 32;       // scan chunk length
constexpr int NC   = 128;      // L / Q
constexpr int TOK  = B2 * L;   // 8192 tokens

typedef __attribute__((ext_vector_type(8))) short bf16x8s;   // 8 bf16 (4 VGPRs)
typedef __attribute__((ext_vector_type(4))) float f32x4;

__device__ __forceinline__ float sigmoidf_(float x) { return 1.f / (1.f + __expf(-x)); }
__device__ __forceinline__ unsigned short f2bf(float f) {
    unsigned int u = __float_as_uint(f);
    unsigned int r = (u + 0x7FFFu + ((u >> 16) & 1u)) >> 16;
    return (unsigned short)r;
}
__device__ __forceinline__ float bf2f(unsigned short s) {
    return __uint_as_float((unsigned int)s << 16);
}

// ---------------- one-shot prep: stats zero + all weight converts/reorders
__global__ __launch_bounds__(256) void prep_all_kernel(
    const float* __restrict__ W_in, const float* __restrict__ W_out,
    const float* __restrict__ cw,
    unsigned short* __restrict__ Winb, unsigned short* __restrict__ Woutb,
    unsigned short* __restrict__ Wrb, float* __restrict__ stats) {
    int idx = blockIdx.x * 256 + threadIdx.x;
    if (blockIdx.x == 0 && threadIdx.x < 4) stats[threadIdx.x] = 0.f;
    if (idx < 262144) {
        Winb[idx] = f2bf(W_in[idx]);
    } else if (idx < 393216) {
        int i = idx - 262144; Woutb[i] = f2bf(W_out[i]);
    } else if (idx < 434176) {
        int i = idx - 393216;                 // conv reorder: [co][ci][kp] -> [co][kp*64+ci]
        int co = i / 320, r = i % 320;
        int kp = r >> 6, ci = r & 63;
        Wrb[i] = f2bf(cw[co * 320 + ci * 5 + kp]);
    }
}

// ---------------- x transpose+convert: x[b][ci][t] -> xTb[b][t][ci] (bf16)
__global__ __launch_bounds__(256) void xpose_kernel(
    const float* __restrict__ x, unsigned short* __restrict__ xTb) {
    __shared__ float tile[64][65];
    int b = blockIdx.y, tb = blockIdx.x * 64, tid = threadIdx.x;
    #pragma unroll
    for (int i = 0; i < 16; ++i) {
        int idx = i * 256 + tid; int ci = idx >> 6, tt = idx & 63;
        tile[ci][tt] = x[((size_t)b * CIN + ci) * T + tb + tt];
    }
    __syncthreads();
    #pragma unroll
    for (int i = 0; i < 16; ++i) {
        int idx = i * 256 + tid; int tt = idx >> 6, ci = idx & 63;
        xTb[((size_t)b * T + tb + tt) * 64 + ci] = f2bf(tile[ci][tt]);
    }
}

// ---------------- conv1d stride2 as bf16-MFMA implicit GEMM + GN stats
__global__ __launch_bounds__(256) void conv_mfma_kernel(
    const unsigned short* __restrict__ xTb, const unsigned short* __restrict__ Wrb,
    const float* __restrict__ cb, float* __restrict__ h, float* __restrict__ stats) {
    const int tid = threadIdx.x;
    const int w = tid >> 6, lane = tid & 63, q = lane >> 4, c = lane & 15;
    const int t0g = blockIdx.x * 64;
    const int t0  = t0g + w * 16;
    const int ct0 = blockIdx.y * 64;
    const int b   = t0g >> 12;
    const int l   = (t0 + c) & (L - 1);
    f32x4 acc[4] = {};
    for (int kc = 0; kc < 320; kc += 32) {
        int kp  = kc >> 6;
        int ci0 = (kc & 63) + q * 8;
        int p = 2 * l + kp - 2;
        bf16x8s a = {};
        if (p >= 0 && p < T)
            a = *(const bf16x8s*)&xTb[((size_t)b * T + p) * 64 + ci0];
        #pragma unroll
        for (int i = 0; i < 4; ++i) {
            bf16x8s bb = *(const bf16x8s*)&Wrb[(size_t)(ct0 + i * 16 + c) * 320 + kc + q * 8];
            acc[i] = __builtin_amdgcn_mfma_f32_16x16x32_bf16(a, bb, acc[i], 0, 0, 0);
        }
    }
    float s = 0.f, ss = 0.f;
    #pragma unroll
    for (int i = 0; i < 4; ++i) {
        int cout = ct0 + i * 16 + c;
        float bias = cb[cout];
        #pragma unroll
        for (int r = 0; r < 4; ++r) {
            int tok = t0 + q * 4 + r;
            float v = acc[i][r] + bias;
            h[(size_t)tok * COUT + cout] = v;
            s += v; ss += v * v;
        }
    }
    #pragma unroll
    for (int off = 32; off; off >>= 1) {
        s  += __shfl_down(s,  off, 64);
        ss += __shfl_down(ss, off, 64);
    }
    if (lane == 0) {
        atomicAdd(&stats[b * 2 + 0], s);
        atomicAdd(&stats[b * 2 + 1], ss);
    }
}

// ---------------- fused GN apply + PReLU (writes h) + layer-0 LayerNorm -> hnb
__global__ __launch_bounds__(256) void gn_ln_kernel(
    float* __restrict__ h, const float* __restrict__ gn_g,
    const float* __restrict__ gn_b, const float* __restrict__ prelu_a,
    const float* __restrict__ stats, unsigned short* __restrict__ hnb,
    const float* __restrict__ lng, const float* __restrict__ lnb) {
    int wave = threadIdx.x >> 6, lane = threadIdx.x & 63;
    int t = blockIdx.x * 4 + wave;
    int b = t >> 12;
    const float n = (float)(L * COUT);
    float mu   = stats[b * 2 + 0] / n;
    float var  = stats[b * 2 + 1] / n - mu * mu;
    float rstd = rsqrtf(var + 1e-5f);
    float a = prelu_a[0];
    float* row = h + (size_t)t * COUT;
    float2 v  = *(const float2*)&row[lane * 2];
    float2 g  = *(const float2*)&gn_g[lane * 2];
    float2 bb = *(const float2*)&gn_b[lane * 2];
    v.x = (v.x - mu) * rstd * g.x + bb.x; v.x = v.x >= 0.f ? v.x : a * v.x;
    v.y = (v.y - mu) * rstd * g.y + bb.y; v.y = v.y >= 0.f ? v.y : a * v.y;
    *(float2*)&row[lane * 2] = v;
    float s = v.x + v.y, ss = v.x * v.x + v.y * v.y;
    #pragma unroll
    for (int off = 32; off; off >>= 1) {
        s  += __shfl_xor(s,  off, 64);
        ss += __shfl_xor(ss, off, 64);
    }
    float mu2 = s * (1.f / 128.f);
    float var2 = ss * (1.f / 128.f) - mu2 * mu2;
    float rstd2 = rsqrtf(var2 + 1e-5f);
    float2 gg = *(const float2*)&lng[lane * 2];
    float2 lb = *(const float2*)&lnb[lane * 2];
    ushort2 o;
    o.x = f2bf((v.x - mu2) * rstd2 * gg.x + lb.x);
    o.y = f2bf((v.y - mu2) * rstd2 * gg.y + lb.y);
    *(ushort2*)&hnb[(size_t)t * COUT + lane * 2] = o;
}

// ------------------------------------------------------ per-token LayerNorm -> bf16
__global__ __launch_bounds__(256) void ln_kernel(
    const float* __restrict__ h, unsigned short* __restrict__ hnb,
    const float* __restrict__ g, const float* __restrict__ bta) {
    int wave = threadIdx.x >> 6, lane = threadIdx.x & 63;
    int t = blockIdx.x * 4 + wave;
    const float* row = h + (size_t)t * COUT;
    float2 v = *(const float2*)&row[lane * 2];
    float s = v.x + v.y, ss = v.x * v.x + v.y * v.y;
    #pragma unroll
    for (int off = 32; off; off >>= 1) {
        s  += __shfl_xor(s,  off, 64);
        ss += __shfl_xor(ss, off, 64);
    }
    float mu = s * (1.f / 128.f);
    float var = ss * (1.f / 128.f) - mu * mu;
    float rstd = rsqrtf(var + 1e-5f);
    float2 gg = *(const float2*)&g[lane * 2];
    float2 bb = *(const float2*)&bta[lane * 2];
    ushort2 o;
    o.x = f2bf((v.x - mu) * rstd * gg.x + bb.x);
    o.y = f2bf((v.y - mu) * rstd * gg.y + bb.y);
    *(ushort2*)&hnb[(size_t)t * COUT + lane * 2] = o;
}

// ---------------- fused inproj MFMA + depthwise conv + SiLU
// x-half blocks (e0<256): compute xp tile (+1 halo token-tile) into LDS, then dwconv -> u (f32).
// z-half blocks (e0>=256): silu(z) -> zb (bf16), as before.
__global__ __launch_bounds__(256) void inproj_dw_kernel(
    const unsigned short* __restrict__ hnb, const unsigned short* __restrict__ Winb,
    const float* __restrict__ cw, const float* __restrict__ cbias,
    float* __restrict__ u0, float* __restrict__ u1,
    unsigned short* __restrict__ zb0, unsigned short* __restrict__ zb1, int layer) {
    __shared__ float xs[80 * 68];    // [window token][channel] pad 68
    const int tid = threadIdx.x;
    const int w = tid >> 6, lane = tid & 63, q = lane >> 4, c = lane & 15;
    const int tBase = blockIdx.x * 64;
    const int nBase = blockIdx.y * 64;
    const int inst = nBase >> 9;
    const int e0 = nBase & 511;
    const int m = layer * 2 + inst;
    const unsigned short* Wb = Winb + (size_t)m * 512 * 128;

    if (e0 >= 256) {   // ---------------- z path ----------------
        const int t0 = tBase + w * 16;
        f32x4 acc[4] = {};
        for (int kc = 0; kc < 128; kc += 32) {
            bf16x8s a = *(const bf16x8s*)&hnb[(size_t)(t0 + c) * 128 + kc + q * 8];
            #pragma unroll
            for (int i = 0; i < 4; ++i) {
                bf16x8s bb = *(const bf16x8s*)&Wb[(size_t)(e0 + i * 16 + c) * 128 + kc + q * 8];
                acc[i] = __builtin_amdgcn_mfma_f32_16x16x32_bf16(a, bb, acc[i], 0, 0, 0);
            }
        }
        unsigned short* zb = inst ? zb1 : zb0;
        #pragma unroll
        for (int i = 0; i < 4; ++i) {
            int eo = (e0 + i * 16 + c) & 255;
            #pragma unroll
            for (int r = 0; r < 4; ++r) {
                int tok = t0 + q * 4 + r;
                float v = acc[i][r];
                zb[(size_t)tok * DI + eo] = f2bf(v * sigmoidf_(v));
            }
        }
        return;
    }
    // ---------------- x path with halo ----------------
    // window: fwd tokens [tBase-16, tBase+63]; bwd tokens [tBase, tBase+79]
    const int winT0 = (inst == 0) ? (tBase - 16) : tBase;
    for (int pass = 0; pass < 2; ++pass) {
        if (pass == 1 && w != 0) break;          // wave 0 handles the halo tile
        int slot = (pass == 0) ? (w + (inst == 0 ? 1 : 0))
                               : ((inst == 0) ? 0 : 4);
        int tokA = winT0 + slot * 16 + c;
        tokA = tokA < 0 ? 0 : (tokA > TOK - 1 ? TOK - 1 : tokA);   // clamp (guards skip invalid taps)
        f32x4 acc[4] = {};
        for (int kc = 0; kc < 128; kc += 32) {
            bf16x8s a = *(const bf16x8s*)&hnb[(size_t)tokA * 128 + kc + q * 8];
            #pragma unroll
            for (int i = 0; i < 4; ++i) {
                bf16x8s bb = *(const bf16x8s*)&Wb[(size_t)(e0 + i * 16 + c) * 128 + kc + q * 8];
                acc[i] = __builtin_amdgcn_mfma_f32_16x16x32_bf16(a, bb, acc[i], 0, 0, 0);
            }
        }
        #pragma unroll
        for (int i = 0; i < 4; ++i)
            #pragma unroll
            for (int r = 0; r < 4; ++r)
                xs[(slot * 16 + q * 4 + r) * 68 + i * 16 + c] = acc[i][r];
    }
    __syncthreads();
    // dwconv from LDS: thread = (tok_sub = tid>>4, ch4 = tid&15), 4 token passes
    const int l0base = tBase & (L - 1);
    const int ch4 = tid & 15;
    const int d0 = e0 + ch4 * 4;
    float4 w0 = *(const float4*)&cw[(size_t)(m * DI + d0 + 0) * 4];
    float4 w1 = *(const float4*)&cw[(size_t)(m * DI + d0 + 1) * 4];
    float4 w2 = *(const float4*)&cw[(size_t)(m * DI + d0 + 2) * 4];
    float4 w3 = *(const float4*)&cw[(size_t)(m * DI + d0 + 3) * 4];
    float4 bias4 = *(const float4*)&cbias[m * DI + d0];
    float* ud = inst ? u1 : u0;
    #pragma unroll
    for (int p = 0; p < 4; ++p) {
        int j = p * 16 + (tid >> 4);             // owned token 0..63
        float4 acc = bias4;
        #pragma unroll
        for (int k = 0; k < 4; ++k) {
            bool valid = (inst == 0) ? (l0base + j - 3 + k >= 0)
                                     : (l0base + j + 3 - k < L);
            if (valid) {
                int wj = (inst == 0) ? (j + 13 + k) : (j + 3 - k);
                float4 v = *(const float4*)&xs[wj * 68 + ch4 * 4];
                float wk0 = ((const float*)&w0)[k], wk1 = ((const float*)&w1)[k];
                float wk2 = ((const float*)&w2)[k], wk3 = ((const float*)&w3)[k];
                acc.x = fmaf(wk0, v.x, acc.x); acc.y = fmaf(wk1, v.y, acc.y);
                acc.z = fmaf(wk2, v.z, acc.z); acc.w = fmaf(wk3, v.w, acc.w);
            }
        }
        acc.x *= sigmoidf_(acc.x); acc.y *= sigmoidf_(acc.y);
        acc.z *= sigmoidf_(acc.z); acc.w *= sigmoidf_(acc.w);
        *(float4*)&ud[(size_t)(tBase + j) * DI + d0] = acc;
    }
}

// ------------------------------------- xproj as GEMM (M=32tok/blk, N=40, K=256)
__global__ __launch_bounds__(256) void xproj_kernel(
    const float* __restrict__ u0, const float* __restrict__ u1,
    const float* __restrict__ Wx, const float* __restrict__ Wdt,
    const float* __restrict__ bdt,
    float* __restrict__ dl0, float* __restrict__ dl1,
    float* __restrict__ Bm0, float* __restrict__ Bm1,
    float* __restrict__ Cm0, float* __restrict__ Cm1, int layer) {
    __shared__ float Ws[40 * 132];   // [e][k-sub] current K slab
    __shared__ float As[128 * 33];   // [k][t] half-K u tile
    __shared__ float xd[32 * 9];     // dt outputs
    const int tid   = threadIdx.x;
    const int tBase = blockIdx.x * 32;
    const int inst  = blockIdx.y;
    const int m     = layer * 2 + inst;
    const float* u  = inst ? u1 : u0;
    const float* Wm = Wx + (size_t)m * 40 * 256;
    const int t  = tid & 31;
    const int eq = tid >> 5;                // 0..7
    float acc[5] = {};
    for (int kc = 0; kc < 256; kc += 128) {
        __syncthreads();
        #pragma unroll
        for (int i = 0; i < 5; ++i) {
            int idx = i * 256 + tid;
            int e = idx >> 5, kq = idx & 31;
            float4 w4 = *(const float4*)&Wm[(size_t)e * 256 + kc + kq * 4];
            float* dstw = &Ws[e * 132 + kq * 4];
            dstw[0] = w4.x; dstw[1] = w4.y; dstw[2] = w4.z; dstw[3] = w4.w;
        }
        #pragma unroll
        for (int i = 0; i < 4; ++i) {
            int flat = i * 256 + tid;
            int tt = flat >> 5, kq = flat & 31;
            float4 v = *(const float4*)&u[(size_t)(tBase + tt) * DI + kc + kq * 4];
            As[(kq * 4 + 0) * 33 + tt] = v.x;
            As[(kq * 4 + 1) * 33 + tt] = v.y;
            As[(kq * 4 + 2) * 33 + tt] = v.z;
            As[(kq * 4 + 3) * 33 + tt] = v.w;
        }
        __syncthreads();
        #pragma unroll 4
        for (int kk = 0; kk < 128; ++kk) {
            float a = As[kk * 33 + t];
            acc[0] = fmaf(a, Ws[(eq     ) * 132 + kk], acc[0]);
            acc[1] = fmaf(a, Ws[(eq +  8) * 132 + kk], acc[1]);
            acc[2] = fmaf(a, Ws[(eq + 16) * 132 + kk], acc[2]);
            acc[3] = fmaf(a, Ws[(eq + 24) * 132 + kk], acc[3]);
            acc[4] = fmaf(a, Ws[(eq + 32) * 132 + kk], acc[4]);
        }
    }
    {
        int tok = tBase + t;
        float* Bm = inst ? Bm1 : Bm0;
        float* Cm = inst ? Cm1 : Cm0;
        xd[t * 9 + eq] = acc[0];
        Bm[(size_t)tok * NST + eq]     = acc[1];
        Bm[(size_t)tok * NST + 8 + eq] = acc[2];
        Cm[(size_t)tok * NST + eq]     = acc[3];
        Cm[(size_t)tok * NST + 8 + eq] = acc[4];
    }
    __syncthreads();
    {
        int d = tid;
        float wr[8];
        #pragma unroll
        for (int r = 0; r < 8; ++r) wr[r] = Wdt[((size_t)m * DI + d) * DTR + r];
        float bb = bdt[m * DI + d];
        float* dl = inst ? dl1 : dl0;
        #pragma unroll 4
        for (int tt = 0; tt < 32; ++tt) {
            float a2 = bb;
            #pragma unroll
            for (int r = 0; r < 8; ++r) a2 = fmaf(xd[tt * 9 + r], wr[r], a2);
            float sp = fmaxf(a2, 0.f) + __logf(1.f + __expf(-fabsf(a2)));
            dl[(size_t)(tBase + tt) * DI + d] = sp;
        }
    }
}

// ---------------------------------------------- scan phase 1: chunk-local
__global__ __launch_bounds__(256) void scan1_kernel(
    const float* __restrict__ dl0, const float* __restrict__ dl1,
    const float* __restrict__ u0,  const float* __restrict__ u1,
    const float* __restrict__ Bm0, const float* __restrict__ Bm1,
    const float* __restrict__ A_log,
    float* __restrict__ hend, float* __restrict__ dsumb, int layer) {
    const int tid = threadIdx.x;
    const int nq = tid & 3, dlane = tid >> 2;
    const int chunk = blockIdx.x & (NC - 1), dtile = blockIdx.x >> 7;
    const int b = blockIdx.y, inst = blockIdx.z;
    const int m = layer * 2 + inst, dir = inst;
    const int d = dtile * 64 + dlane;
    const float* dl = inst ? dl1 : dl0;
    const float* u  = inst ? u1  : u0;
    const float* Bm = inst ? Bm1 : Bm0;
    float4 av = *(const float4*)&A_log[((size_t)m * DI + d) * NST + nq * 4];
    const float a0 = -expf(av.x), a1 = -expf(av.y), a2 = -expf(av.z), a3 = -expf(av.w);
    const int s0 = chunk * Q;
    const int l0 = dir ? (L - 1 - s0) : s0;
    const int stp = dir ? -1 : 1;
    long iDU = ((long)(b * L + l0)) * DI + d;
    int  iB  = ((b * L + l0) << 4) + nq * 4;
    const long sDU = (long)stp * DI;
    const int  sB  = stp * NST;
    float h0 = 0.f, h1 = 0.f, h2 = 0.f, h3 = 0.f, dsum = 0.f;
    #pragma unroll 4
    for (int t = 0; t < Q; ++t) {
        float dlt = dl[iDU], uu = u[iDU];
        float4 bm = *(const float4*)&Bm[iB];
        float du = dlt * uu;
        h0 = fmaf(__expf(dlt * a0), h0, du * bm.x);
        h1 = fmaf(__expf(dlt * a1), h1, du * bm.y);
        h2 = fmaf(__expf(dlt * a2), h2, du * bm.z);
        h3 = fmaf(__expf(dlt * a3), h3, du * bm.w);
        dsum += dlt;
        iDU += sDU; iB += sB;
    }
    size_t oh = (((size_t)(inst * 2 + b) * DI + d) * NC + chunk) * NST + nq * 4;
    *(float4*)&hend[oh] = make_float4(h0, h1, h2, h3);
    if (nq == 0) dsumb[((size_t)(inst * 2 + b) * NC + chunk) * DI + d] = dsum;
}

// ---------------------------------------------- scan combine (in-place prefix)
__global__ __launch_bounds__(256) void combine_kernel(
    float* __restrict__ hend, const float* __restrict__ dsumb,
    const float* __restrict__ A_log, int layer) {
    int flat = blockIdx.x * 256 + threadIdx.x;   // 16384
    int n = flat & 15;
    int d = (flat >> 4) & 255;
    int b = (flat >> 12) & 1;
    int inst = flat >> 13;
    int m = layer * 2 + inst;
    float a = -expf(A_log[((size_t)m * DI + d) * NST + n]);
    size_t baseE = (((size_t)(inst * 2 + b) * DI + d) * NC) * NST + n;
    size_t baseD = ((size_t)(inst * 2 + b) * NC) * DI + d;
    float hc = 0.f;
    #pragma unroll 4
    for (int c = 0; c < NC; ++c) {
        float tmp = hend[baseE + (size_t)c * NST];
        hend[baseE + (size_t)c * NST] = hc;
        float ds = dsumb[baseD + (size_t)c * DI];
        hc = fmaf(__expf(a * ds), hc, tmp);
    }
}

// ------------- scan phase 2: full scan + y + gate (bf16 z, yg written bf16 IN PLACE over z)
__global__ __launch_bounds__(256) void scan2_kernel(
    const float* __restrict__ dl0, const float* __restrict__ dl1,
    const float* __restrict__ u0,  const float* __restrict__ u1,
    const float* __restrict__ Bm0, const float* __restrict__ Bm1,
    const float* __restrict__ Cm0, const float* __restrict__ Cm1,
    unsigned short* __restrict__ zb0, unsigned short* __restrict__ zb1,
    const float* __restrict__ hin, const float* __restrict__ A_log,
    const float* __restrict__ Dp, int layer) {
    const int tid = threadIdx.x;
    const int nq = tid & 3, dlane = tid >> 2;
    const int chunk = blockIdx.x & (NC - 1), dtile = blockIdx.x >> 7;
    const int b = blockIdx.y, inst = blockIdx.z;
    const int m = layer * 2 + inst, dir = inst;
    const int d = dtile * 64 + dlane;
    const float* dl = inst ? dl1 : dl0;
    const float* u  = inst ? u1  : u0;
    const float* Bm = inst ? Bm1 : Bm0;
    const float* Cm = inst ? Cm1 : Cm0;
    unsigned short* zs = inst ? zb1 : zb0;   // read z, overwrite with yg (same lane)
    float4 av = *(const float4*)&A_log[((size_t)m * DI + d) * NST + nq * 4];
    const float a0 = -expf(av.x), a1 = -expf(av.y), a2 = -expf(av.z), a3 = -expf(av.w);
    const float dpar = Dp[m * DI + d];
    const int s0 = chunk * Q;
    const int l0 = dir ? (L - 1 - s0) : s0;
    const int stp = dir ? -1 : 1;
    long iDU = ((long)(b * L + l0)) * DI + d;
    int  iB  = ((b * L + l0) << 4) + nq * 4;
    const long sDU = (long)stp * DI;
    const int  sB  = stp * NST;
    float4 hv = *(const float4*)&hin[(((size_t)(inst * 2 + b) * DI + d) * NC + chunk) * NST + nq * 4];
    float h0 = hv.x, h1 = hv.y, h2 = hv.z, h3 = hv.w;
    #pragma unroll 4
    for (int t = 0; t < Q; ++t) {
        float dlt = dl[iDU], uu = u[iDU];
        float4 bm = *(const float4*)&Bm[iB];
        float4 cm = *(const float4*)&Cm[iB];
        float du = dlt * uu;
        h0 = fmaf(__expf(dlt * a0), h0, du * bm.x);
        h1 = fmaf(__expf(dlt * a1), h1, du * bm.y);
        h2 = fmaf(__expf(dlt * a2), h2, du * bm.z);
        h3 = fmaf(__expf(dlt * a3), h3, du * bm.w);
        float yp = h0 * cm.x + h1 * cm.y + h2 * cm.z + h3 * cm.w;
        yp += __shfl_xor(yp, 1, 4);
        yp += __shfl_xor(yp, 2, 4);
        if (nq == 0) {
            float zv = bf2f(zs[iDU]);
            zs[iDU] = f2bf(fmaf(uu, dpar, yp) * zv);
        }
        iDU += sDU; iB += sB;
    }
}

// ---------------- outproj as bf16-MFMA GEMM (both insts summed) + residual into h
__global__ __launch_bounds__(256) void outproj_mfma_kernel(
    const unsigned short* __restrict__ ygb0, const unsigned short* __restrict__ ygb1,
    const unsigned short* __restrict__ Woutb, float* __restrict__ h, int layer) {
    const int tid = threadIdx.x;
    const int w = tid >> 6, lane = tid & 63, q = lane >> 4, c = lane & 15;
    const int t0 = blockIdx.x * 64 + w * 16;
    const int ct0 = blockIdx.y * 32;
    f32x4 acc[2] = {};
    #pragma unroll
    for (int inst = 0; inst < 2; ++inst) {
        const unsigned short* yg = inst ? ygb1 : ygb0;
        const unsigned short* Wb = Woutb + (size_t)(layer * 2 + inst) * COUT * DI;
        for (int kc = 0; kc < 256; kc += 32) {
            bf16x8s a = *(const bf16x8s*)&yg[(size_t)(t0 + c) * DI + kc + q * 8];
            #pragma unroll
            for (int i = 0; i < 2; ++i) {
                bf16x8s bb = *(const bf16x8s*)&Wb[(size_t)(ct0 + i * 16 + c) * DI + kc + q * 8];
                acc[i] = __builtin_amdgcn_mfma_f32_16x16x32_bf16(a, bb, acc[i], 0, 0, 0);
            }
        }
    }
    #pragma unroll
    for (int i = 0; i < 2; ++i) {
        int cout = ct0 + i * 16 + c;
        #pragma unroll
        for (int r = 0; r < 4; ++r) {
            int tok = t0 + q * 4 + r;
            h[(size_t)tok * COUT + cout] += acc[i][r];
        }
    }
}

// ------------------------------------------------ final [B,L,C] -> [B,C,L]
__global__ __launch_bounds__(256) void transpose_kernel(
    const float* __restrict__ h, float* __restrict__ out) {
    __shared__ float tile[32][33];
    int lt0 = blockIdx.x * 32, ct0 = blockIdx.y * 32, b = blockIdx.z;
    int c = threadIdx.x & 31, r = threadIdx.x >> 5;
    #pragma unroll
    for (int j = 0; j < 4; ++j) {
        int ll = r + 8 * j;
        tile[ll][c] = h[((size_t)b * L + lt0 + ll) * COUT + ct0 + c];
    }
    __syncthreads();
    #pragma unroll
    for (int j = 0; j < 4; ++j) {
        int cc = r + 8 * j;
        out[((size_t)b * COUT + ct0 + cc) * L + lt0 + c] = tile[c][cc];
    }
}

// ======================================================================
extern "C" void kernel_launch(void* const* d_in, const int* in_sizes, int n_in,
                              void* d_out, int out_size, void* d_ws, size_t ws_size,
                              hipStream_t stream) {
    const float* x        = (const float*)d_in[0];
    const float* conv_w   = (const float*)d_in[1];
    const float* conv_b   = (const float*)d_in[2];
    const float* gn_g     = (const float*)d_in[3];
    const float* gn_b     = (const float*)d_in[4];
    const float* prelu_a  = (const float*)d_in[5];
    const float* ln_g     = (const float*)d_in[6];
    const float* ln_b     = (const float*)d_in[7];
    const float* W_in     = (const float*)d_in[8];
    const float* conv1d_w = (const float*)d_in[9];
    const float* conv1d_b = (const float*)d_in[10];
    const float* W_xproj  = (const float*)d_in[11];
    const float* W_dt     = (const float*)d_in[12];
    const float* b_dt     = (const float*)d_in[13];
    const float* A_log    = (const float*)d_in[14];
    const float* D_param  = (const float*)d_in[15];
    const float* W_out    = (const float*)d_in[16];

    float* ws = (float*)d_ws;
    float* h     = ws;                         // [B,L,128]               1,048,576
    unsigned short* zb0 = (unsigned short*)(ws + 5242880);   // [B,L,256] bf16; silu(z) then yg in-place
    unsigned short* zb1 = (unsigned short*)(ws + 6291456);   // bf16
    float* u0    = ws + 7340032;               // [B,L,256]               2,097,152
    float* u1    = ws + 9437184;
    float* dl0   = ws + 11534336;
    float* dl1   = ws + 13631488;
    float* Bm0   = ws + 15728640;              // [B,L,16]
    float* Bm1   = ws + 15859712;
    float* Cm0   = ws + 15990784;
    float* Cm1   = ws + 16121856;
    float* hend  = ws + 16252928;              // [2,B,256,NC=128,16] = 2,097,152
    float* dsumb = ws + 18350080;              // [2,B,NC,256] = 131,072
    unsigned short* Winb  = (unsigned short*)(ws + 18481152); // 262,144 bf16 (131,072 f)
    unsigned short* Wrb   = (unsigned short*)(ws + 18612224); // 40,960 bf16 (20,480 f)
    unsigned short* Woutb = (unsigned short*)(ws + 18632704); // 131,072 bf16 (65,536 f)
    float* stats = ws + 18698240;              // [4]
    unsigned short* hnb = (unsigned short*)hend;             // 1M bf16 (hend dead outside scans)
    unsigned short* xTb = zb0;                               // 1M bf16 (pre-loop only)

    prep_all_kernel<<<1696, 256, 0, stream>>>(W_in, W_out, conv_w, Winb, Woutb, Wrb, stats);
    xpose_kernel<<<dim3(T / 64, B2), 256, 0, stream>>>(x, xTb);
    conv_mfma_kernel<<<dim3(TOK / 64, COUT / 64), 256, 0, stream>>>(xTb, Wrb, conv_b, h, stats);
    gn_ln_kernel<<<TOK / 4, 256, 0, stream>>>(h, gn_g, gn_b, prelu_a, stats, hnb, ln_g, ln_b);

    for (int layer = 0; layer < 2; ++layer) {
        if (layer == 1)
            ln_kernel<<<TOK / 4, 256, 0, stream>>>(h, hnb, ln_g + COUT, ln_b + COUT);
        inproj_dw_kernel<<<dim3(TOK / 64, 16), 256, 0, stream>>>(hnb, Winb, conv1d_w, conv1d_b,
                                                                 u0, u1, zb0, zb1, layer);
        xproj_kernel<<<dim3(TOK / 32, 2), 256, 0, stream>>>(u0, u1, W_xproj, W_dt, b_dt,
                                                            dl0, dl1, Bm0, Bm1, Cm0, Cm1, layer);
        scan1_kernel<<<dim3(NC * 4, B2, 2), 256, 0, stream>>>(dl0, dl1, u0, u1, Bm0, Bm1,
                                                              A_log, hend, dsumb, layer);
        combine_kernel<<<64, 256, 0, stream>>>(hend, dsumb, A_log, layer);
        scan2_kernel<<<dim3(NC * 4, B2, 2), 256, 0, stream>>>(dl0, dl1, u0, u1, Bm0, Bm1, Cm0, Cm1,
                                                              zb0, zb1, hend, A_log, D_param, layer);
        outproj_mfma_kernel<<<dim3(TOK / 64, 4), 256, 0, stream>>>(zb0, zb1, Woutb, h, layer);
    }
    transpose_kernel<<<dim3(L / 32, COUT / 32, B2), 256, 0, stream>>>(h, (float*)d_out);
}